// Round 18
// baseline (1083.622 us; speedup 1.0000x reference)
//
#include <hip/hip_runtime.h>
#include <math.h>

// RPN forward: fused conv3x3+relu (f64 MFMA implicit GEMM, layout-probed,
// raw-weight register loads, dbuf input LDS, 8ci/barrier) -> fused 1x1
// heads -> [topk+decode+per-group sort+NMS+compact] (10 blocks) ->
// per-image merge select. 4 dispatches (R15 structure = best, 1002us).
// Precision: f64 everywhere decision-relevant (absmax 0 through R17).
// R17 analysis: topk's ~240us = clustered logits (|logit|<~0.2) make
// early radix digits degenerate -> all lanes atomicAdd the SAME LDS bin
// (64-way serialization x 30 keys x several passes). R18: wave-aggregated
// histogram atomics (leader/ballot; 1 atomic per distinct digit per wave).
// Histogram counts identical -> selection bit-identical.

#define N_IMG 2
#define C_CH  256
#define D_PER 2147
#define K_TOT 4294
#define CONV_BLOCKS 1912
#define CPX 239              // CONV_BLOCKS / 8 XCDs (exact)

typedef double v4d __attribute__((ext_vector_type(4)));

__constant__ int c_Ml[5]     = {30000, 7500, 1875, 507, 147};
__constant__ int c_kl[5]     = {500, 500, 500, 500, 147};
__constant__ int c_logoff[5] = {0, 60000, 75000, 78750, 79764};   // 6*cumE
__constant__ int c_regoff[5] = {0, 240000, 300000, 315000, 319056}; // 24*cumE
__constant__ int c_fs[5]     = {100, 50, 25, 13, 7};
__constant__ int c_npt[5]    = {13, 7, 4, 2, 1};
__constant__ int c_E[5]      = {10000, 2500, 625, 169, 49};
__constant__ int c_cumbl[6]  = {0, 1352, 1744, 1872, 1904, 1912};
__constant__ int c_hcum[6]   = {0, 157, 197, 207, 210, 211};
__constant__ size_t c_hoff[5] = {0, 5120000, 6400000, 6720000, 6806528};

// ------- fused conv3x3 (SAME) + bias + relu via f64 MFMA -----------------
template <typename T>
__global__ __launch_bounds__(256) void conv_fused_kernel(
    const float* __restrict__ x0, const float* __restrict__ x1,
    const float* __restrict__ x2, const float* __restrict__ x3,
    const float* __restrict__ x4, const float* __restrict__ wraw,
    const float* __restrict__ bias, T* __restrict__ h) {
  __shared__ __align__(16) double s_in[2][960];  // dbuf [ci8][10x12]
  int tid = threadIdx.x;
  int bid = (blockIdx.x & 7) * CPX + (blockIdx.x >> 3);  // XCD swizzle
  int l = 0;
  while (bid >= c_cumbl[l + 1]) ++l;
  int r = bid - c_cumbl[l];
  int fs = c_fs[l], npt = c_npt[l];
  int tiles = npt * npt;
  int tile = r % tiles;
  int cn = r / tiles;
  int cobi = cn & 3, n = cn >> 2;
  int ptx = tile % npt, pty = tile / npt;
  int px0 = ptx * 8, py0 = pty * 8;
  int E = fs * fs;
  const float* xl;
  switch (l) {
    case 0: xl = x0; break;
    case 1: xl = x1; break;
    case 2: xl = x2; break;
    case 3: xl = x3; break;
    default: xl = x4; break;
  }
  const float* xn = xl + (size_t)n * C_CH * E;
  T* hl = h + c_hoff[l];

  int lane = tid & 63;
  int wv = tid >> 6;
  int lx = lane & 15;
  int lk = lane >> 4;

  // ---- layout calibration probes (verified R12) ----
  double ind0 = (lk == 0) ? 1.0 : 0.0;
  v4d pr1 = __builtin_amdgcn_mfma_f64_16x16x4f64((double)lx, ind0,
                                                 (v4d)0.0, 0, 0, 0);
  v4d pr2 = __builtin_amdgcn_mfma_f64_16x16x4f64(ind0, (double)lx,
                                                 (v4d)0.0, 0, 0, 0);
  int coL[4], pxL[4];
#pragma unroll
  for (int q = 0; q < 4; ++q) {
    coL[q] = (int)pr1[q];
    pxL[q] = (int)pr2[q];
  }

  int in_dst[4], in_src[4];
#pragma unroll
  for (int it = 0; it < 4; ++it) {
    int idx = tid + it * 256;
    in_dst[it] = -1;
    in_src[it] = -1;
    if (idx < 800) {
      int ci = idx / 100, rr2 = idx % 100;
      int hy = rr2 / 10, hx = rr2 % 10;
      int gy = py0 - 1 + hy, gx = px0 - 1 + hx;
      in_dst[it] = ci * 120 + hy * 12 + hx;
      if (gy >= 0 && gy < fs && gx >= 0 && gx < fs)
        in_src[it] = ci * E + gy * fs + gx;
    }
  }

  int bOff[4];
#pragma unroll
  for (int p = 0; p < 4; ++p) {
    int pxidx = p * 16 + lx;
    bOff[p] = lk * 120 + (pxidx >> 3) * 12 + (pxidx & 7);
  }

  v4d acc[4];
#pragma unroll
  for (int p = 0; p < 4; ++p) acc[p] = (v4d)0.0;

  const float* wp0 = wraw + (size_t)(cobi * 64 + wv * 16 + lx) * 2304;

  float wcur[18], wnxt[18];
  {
    const float* a = wp0 + lk * 9;
    const float* b = wp0 + (4 + lk) * 9;
#pragma unroll
    for (int t = 0; t < 9; ++t) {
      wcur[t] = a[t];
      wcur[9 + t] = b[t];
    }
  }
  {
    float v0[4];
#pragma unroll
    for (int it = 0; it < 4; ++it)
      v0[it] = (in_dst[it] >= 0 && in_src[it] >= 0) ? xn[in_src[it]] : 0.f;
#pragma unroll
    for (int it = 0; it < 4; ++it)
      if (in_dst[it] >= 0) s_in[0][in_dst[it]] = (double)v0[it];
  }
  __syncthreads();

  for (int it = 0; it < 32; ++it) {
    int buf = it & 1;
    bool more = (it + 1 < 32);
    float inx[4];
    if (more) {
      const float* xc1 = xn + (size_t)(it + 1) * 8 * E;
#pragma unroll
      for (int s = 0; s < 4; ++s)
        inx[s] = (in_dst[s] >= 0 && in_src[s] >= 0) ? xc1[in_src[s]] : 0.f;
      const float* a = wp0 + ((it + 1) * 8 + lk) * 9;
      const float* b = wp0 + ((it + 1) * 8 + 4 + lk) * 9;
#pragma unroll
      for (int t = 0; t < 9; ++t) {
        wnxt[t] = a[t];
        wnxt[9 + t] = b[t];
      }
    }
    const double* bbA = s_in[buf];
    const double* bbB = s_in[buf] + 480;
#pragma unroll
    for (int ky = 0; ky < 3; ++ky) {
#pragma unroll
      for (int kx = 0; kx < 3; ++kx) {
        int tap = ky * 3 + kx;
        int boff = ky * 12 + kx;
        double avA = (double)wcur[tap];
#pragma unroll
        for (int p = 0; p < 4; ++p) {
          acc[p] = __builtin_amdgcn_mfma_f64_16x16x4f64(
              avA, bbA[bOff[p] + boff], acc[p], 0, 0, 0);
        }
      }
    }
#pragma unroll
    for (int ky = 0; ky < 3; ++ky) {
#pragma unroll
      for (int kx = 0; kx < 3; ++kx) {
        int tap = ky * 3 + kx;
        int boff = ky * 12 + kx;
        double avB = (double)wcur[9 + tap];
#pragma unroll
        for (int p = 0; p < 4; ++p) {
          acc[p] = __builtin_amdgcn_mfma_f64_16x16x4f64(
              avB, bbB[bOff[p] + boff], acc[p], 0, 0, 0);
        }
      }
    }
    if (more) {
      double* db = s_in[buf ^ 1];
#pragma unroll
      for (int s = 0; s < 4; ++s)
        if (in_dst[s] >= 0) db[in_dst[s]] = (double)inx[s];
#pragma unroll
      for (int t = 0; t < 18; ++t) wcur[t] = wnxt[t];
    }
    __syncthreads();
  }

#pragma unroll
  for (int p = 0; p < 4; ++p) {
#pragma unroll
    for (int rr2 = 0; rr2 < 4; ++rr2) {
      int pxidx = p * 16 + pxL[rr2];
      int gy = py0 + (pxidx >> 3), gx = px0 + (pxidx & 7);
      int co = cobi * 64 + wv * 16 + coL[rr2];
      if (gy < fs && gx < fs) {
        double v = acc[p][rr2] + (double)bias[co];
        hl[((size_t)n * C_CH + co) * E + gy * fs + gx] = (T)fmax(v, 0.0);
      }
    }
  }
}

// ------- fused 1x1 heads: 64 px x 4 c-groups per block, LDS reduce -------
template <typename T>
__global__ __launch_bounds__(256) void heads_fused_kernel(
    const T* __restrict__ h, const float* __restrict__ logw,
    const float* __restrict__ logb, const float* __restrict__ regw,
    const float* __restrict__ regb, double* __restrict__ logits,
    double* __restrict__ regs) {
  __shared__ float s_wh[256][16];
  __shared__ double s_red[4][15][64];
  int tid = threadIdx.x;
  int n = blockIdx.y;
  int cidx = blockIdx.x;
  int l = 0;
  while (cidx >= c_hcum[l + 1]) ++l;
  int chunk = cidx - c_hcum[l];
  int E = c_E[l];
  int px0 = chunk * 64;
  const T* hl = h + c_hoff[l];
  double* logits_l = logits + c_logoff[l];
  double* regs_l = regs + c_regoff[l];

  for (int idx = tid; idx < 4096; idx += 256) {
    int c = idx >> 4, j = idx & 15;
    float v = 0.f;
    if (j < 3) v = logw[j * 256 + c];
    else if (j < 15) v = regw[(j - 3) * 256 + c];
    s_wh[c][j] = v;
  }
  __syncthreads();

  int p = tid & 63, c4 = tid >> 6;
  int pix = px0 + p;
  bool act = pix < E;
  double acc[15];
#pragma unroll
  for (int j = 0; j < 15; j++) acc[j] = 0.0;
  if (act) {
    const T* hp = hl + ((size_t)n * C_CH + c4 * 64) * E + pix;
    for (int cc = 0; cc < 64; ++cc) {
      double hv = (double)hp[(size_t)cc * E];
      const float* wr = &s_wh[c4 * 64 + cc][0];
#pragma unroll
      for (int j = 0; j < 15; j++)
        acc[j] = fma((double)wr[j], hv, acc[j]);
    }
  }
#pragma unroll
  for (int j = 0; j < 15; j++) s_red[c4][j][p] = acc[j];
  __syncthreads();
  if (act) {
    int M = E * 3;
    for (int j = c4; j < 15; j += 4) {
      double v = s_red[0][j][p] + s_red[1][j][p] + s_red[2][j][p] +
                 s_red[3][j][p];
      if (j < 3) {
        logits_l[(size_t)n * M + pix * 3 + j] = v + (double)logb[j];
      } else {
        int rj = j - 3, a = rj >> 2, coord = rj & 3;
        regs_l[((size_t)n * M + pix * 3 + a) * 4 + coord] =
            v + (double)regb[rj];
      }
    }
  }
}

// ------- topk + decode + per-group sort + NMS + compact (10 blocks) ------
__device__ __forceinline__ unsigned long long d2key(double v) {
  unsigned long long ub = (unsigned long long)__double_as_longlong(v);
  return (ub >> 63) ? ~ub : (ub | 0x8000000000000000ull);
}

#define TK_CH 30
union TkShared {
  struct {
    int histw[16][256];
    int hist[256];
    int sgt[1024];
    int seq[1024];
  } a;
  struct {
    unsigned long long u[512];
    int idx[512];
    int keep[512];
    int ps[512];
    int m;
    double bx[512][4];
    unsigned long long mask[512][8];
  } b;
};

__global__ __launch_bounds__(1024) void topk_nms_kernel(
    const double* __restrict__ logits, const double* __restrict__ regs,
    const float* __restrict__ p0, const float* __restrict__ p1,
    const float* __restrict__ p2, const float* __restrict__ p3,
    const float* __restrict__ p4, const int* __restrict__ imsizes,
    double* __restrict__ g_box, unsigned long long* __restrict__ g_u,
    int* __restrict__ g_cnt) {
  __shared__ TkShared sh;
  __shared__ int s_sel[512];
  __shared__ unsigned long long s_prefix;
  __shared__ int s_r;
  int bid = blockIdx.x;
  int n = bid / 5, l = bid % 5;
  int M = c_Ml[l], k = c_kl[l];
  const double* lg = logits + c_logoff[l] + (size_t)n * M;
  int tid = threadIdx.x;
  int lane = tid & 63;
  if (tid == 0) { s_prefix = 0ull; s_r = k; }

  int chunk = (M + 1023) >> 10;     // <= 30
  int i0 = tid * chunk, i1 = min(M, i0 + chunk);
  int cnt = i1 - i0;
  if (cnt < 0) cnt = 0;
  unsigned long long kv[TK_CH];
#pragma unroll
  for (int q = 0; q < TK_CH; q++)
    if (q < cnt) kv[q] = d2key(lg[i0 + q]);
  int wid = tid >> 6;
  __syncthreads();

  for (int pass = 0; pass < 8; ++pass) {
    int shift = 56 - pass * 8;
    for (int i = tid; i < 4096; i += 1024) ((int*)sh.a.histw)[i] = 0;
    __syncthreads();
    unsigned long long pfx = s_prefix;
    int rr = s_r;
    // wave-aggregated histogram: clustered logits make digits degenerate;
    // 1 atomic per distinct digit per wave instead of per key.
    for (int q = 0; q < TK_CH; q++) {
      bool part = false;
      int dig = 0;
      if (q < cnt) {
        unsigned long long u = kv[q];
        if (pass == 0 || (u >> (shift + 8)) == pfx) {
          part = true;
          dig = (int)((u >> shift) & 255ull);
        }
      }
      if (part) {
        while (true) {
          unsigned long long act = __ballot(1);
          int leader = (int)(__ffsll((long long)act) - 1);
          int dl = __shfl(dig, leader);
          bool mine = (dig == dl);
          unsigned long long same = __ballot(mine);
          if (lane == leader)
            atomicAdd(&sh.a.histw[wid][dl], (int)__popcll(same));
          if (mine) break;
        }
      }
    }
    __syncthreads();
    if (tid < 256) {
      int s = 0;
#pragma unroll
      for (int w = 0; w < 16; w++) s += sh.a.histw[w][tid];
      sh.a.hist[tid] = s;
    }
    __syncthreads();
    if (tid == 0) {
      int s = 0, beta = 0;
      for (int b = 255; b >= 0; --b) {
        if (s + sh.a.hist[b] >= rr) { beta = b; break; }
        s += sh.a.hist[b];
      }
      s_prefix = (pfx << 8) | (unsigned long long)beta;
      s_r = rr - s;
    }
    __syncthreads();
  }
  unsigned long long T = s_prefix;
  int need = s_r;
  int cgt = 0, ceq = 0;
#pragma unroll
  for (int q = 0; q < TK_CH; q++) {
    if (q < cnt) {
      cgt += (kv[q] > T);
      ceq += (kv[q] == T);
    }
  }
  sh.a.sgt[tid] = cgt;
  sh.a.seq[tid] = ceq;
  __syncthreads();
  for (int o = 1; o < 1024; o <<= 1) {
    int a = (tid >= o) ? sh.a.sgt[tid - o] : 0;
    int b2 = (tid >= o) ? sh.a.seq[tid - o] : 0;
    __syncthreads();
    sh.a.sgt[tid] += a;
    sh.a.seq[tid] += b2;
    __syncthreads();
  }
  int gt_total = sh.a.sgt[1023];
  int pg = sh.a.sgt[tid] - cgt, pe = sh.a.seq[tid] - ceq;
#pragma unroll
  for (int q = 0; q < TK_CH; q++) {
    if (q < cnt) {
      unsigned long long u = kv[q];
      if (u > T) {
        s_sel[pg++] = i0 + q;
      } else if (u == T) {
        if (pe < need) s_sel[gt_total + pe] = i0 + q;
        pe++;
      }
    }
  }
  __syncthreads();

  const float* pp;
  switch (l) {
    case 0: pp = p0; break;
    case 1: pp = p1; break;
    case 2: pp = p2; break;
    case 3: pp = p3; break;
    default: pp = p4; break;
  }
  const double* regs_l = regs + c_regoff[l];
  double imh = (double)imsizes[n * 2 + 0], imw = (double)imsizes[n * 2 + 1];
  const double BCLIP = 4.1351665567423560;
  if (tid < 512) {
    unsigned long long key = 0ull;
    sh.b.idx[tid] = tid;
    sh.b.keep[tid] = 0;
    if (tid < k) {
      int aidx = s_sel[tid];
      double lv = lg[aidx];
      double obj = 1.0 / (1.0 + exp(-lv));
      const double* rp = regs_l + ((size_t)n * M + aidx) * 4;
      const float* pr = pp + (size_t)aidx * 4;
      double px1 = pr[0], py1 = pr[1], px2 = pr[2], py2 = pr[3];
      double pw = px2 - px1, ph = py2 - py1;
      double pcx = px1 + 0.5 * pw, pcy = py1 + 0.5 * ph;
      double dx = rp[0], dy = rp[1];
      double dw = fmin(rp[2], BCLIP), dh = fmin(rp[3], BCLIP);
      double cx = dx * pw + pcx, cy = dy * ph + pcy;
      double w = exp(dw) * pw, hh = exp(dh) * ph;
      double x1 = cx - 0.5 * w, y1 = cy - 0.5 * hh;
      double x2 = cx + 0.5 * w, y2 = cy + 0.5 * hh;
      x1 = fmin(fmax(x1, 0.0), imw);
      x2 = fmin(fmax(x2, 0.0), imw);
      y1 = fmin(fmax(y1, 0.0), imh);
      y2 = fmin(fmax(y2, 0.0), imh);
      bool valid = (obj >= 0.5) && ((x2 - x1) >= 1.0) && ((y2 - y1) >= 1.0);
      sh.b.bx[tid][0] = x1;
      sh.b.bx[tid][1] = y1;
      sh.b.bx[tid][2] = x2;
      sh.b.bx[tid][3] = y2;
      if (valid) key = d2key(obj);
    }
    sh.b.u[tid] = key;
  }
  if (tid == 0) sh.b.m = 0;
  __syncthreads();

  for (int kk = 2; kk <= 512; kk <<= 1) {
    for (int j = kk >> 1; j > 0; j >>= 1) {
      if (tid < 512) {
        int i = tid, ixj = i ^ j;
        if (ixj > i) {
          unsigned long long ua = sh.b.u[i], ub = sh.b.u[ixj];
          int ia = sh.b.idx[i], ib = sh.b.idx[ixj];
          bool up = ((i & kk) == 0);
          bool aAfterB = (ua < ub) || (ua == ub && ia > ib);
          bool sw = up ? aAfterB : !aAfterB && (ua != ub || ia != ib);
          if (sw) {
            sh.b.u[i] = ub; sh.b.u[ixj] = ua;
            sh.b.idx[i] = ib; sh.b.idx[ixj] = ia;
          }
        }
      }
      __syncthreads();
    }
  }
  if (tid < 512) {
    if (sh.b.u[tid] != 0ull && (tid == 511 || sh.b.u[tid + 1] == 0ull))
      sh.b.m = tid + 1;
  }
  __syncthreads();
  int m = sh.b.m;

  if (tid < 512 && tid < m) {
    int i = tid;
    const double* A = sh.b.bx[sh.b.idx[i]];
    double ax1 = A[0], ay1 = A[1], ax2 = A[2], ay2 = A[3];
    double areaA = (ax2 - ax1) * (ay2 - ay1);
    unsigned long long row[8] = {0, 0, 0, 0, 0, 0, 0, 0};
    for (int j = i + 1; j < m; ++j) {
      const double* B = sh.b.bx[sh.b.idx[j]];
      double bx1 = B[0], by1 = B[1], bx2 = B[2], by2 = B[3];
      double areaB = (bx2 - bx1) * (by2 - by1);
      double lx = fmax(ax1, bx1), ly = fmax(ay1, by1);
      double rx = fmin(ax2, bx2), ry = fmin(ay2, by2);
      double iw = fmax(rx - lx, 0.0), ih = fmax(ry - ly, 0.0);
      double inter = iw * ih;
      double iou = inter / (areaA + areaB - inter + 1e-9);
      if (iou > 0.7) row[j >> 6] |= (1ull << (j & 63));
    }
#pragma unroll
    for (int w2 = 0; w2 < 8; ++w2) sh.b.mask[i][w2] = row[w2];
  }
  __syncthreads();

  if (tid == 0) {
    unsigned long long remv[8] = {0, 0, 0, 0, 0, 0, 0, 0};
    for (int i = 0; i < m; ++i) {
      if (!((remv[i >> 6] >> (i & 63)) & 1ull)) {
        sh.b.keep[i] = 1;
#pragma unroll
        for (int w2 = 0; w2 < 8; ++w2) remv[w2] |= sh.b.mask[i][w2];
      }
    }
  }
  __syncthreads();

  if (tid < 512) sh.b.ps[tid] = sh.b.keep[tid];
  __syncthreads();
  for (int o = 1; o < 512; o <<= 1) {
    int v = 0;
    if (tid < 512 && tid >= o) v = sh.b.ps[tid - o];
    __syncthreads();
    if (tid < 512) sh.b.ps[tid] += v;
    __syncthreads();
  }
  if (tid < 512 && sh.b.keep[tid]) {
    int pos = sh.b.ps[tid] - 1;
    const double* B = sh.b.bx[sh.b.idx[tid]];
    size_t gbase = (size_t)bid * 512 + pos;
#pragma unroll
    for (int q = 0; q < 4; q++) g_box[gbase * 4 + q] = B[q];
    g_u[gbase] = sh.b.u[tid];
  }
  if (tid == 0) g_cnt[bid] = (m > 0) ? sh.b.ps[511] : 0;
}

// ------- per-image select: 5-way merge of sorted kept lists, top 100 -----
__global__ __launch_bounds__(256) void select_kernel(
    const double* __restrict__ g_box, const unsigned long long* __restrict__ g_u,
    const int* __restrict__ g_cnt, float* __restrict__ out) {
  __shared__ unsigned long long s_u[5][512];
  __shared__ int s_pick[100];
  __shared__ int s_total;
  int n = blockIdx.x;
  int tid = threadIdx.x;
  int cnts[5];
#pragma unroll
  for (int l = 0; l < 5; l++) cnts[l] = g_cnt[n * 5 + l];
  for (int idx = tid; idx < 5 * 512; idx += 256) {
    int l = idx >> 9, r = idx & 511;
    s_u[l][r] = (r < cnts[l]) ? g_u[(size_t)(n * 5 + l) * 512 + r] : 0ull;
  }
  __syncthreads();
  if (tid == 0) {
    int hd[5] = {0, 0, 0, 0, 0};
    int t = 0;
    while (t < 100) {
      int bl = -1;
      unsigned long long bu = 0ull;
      for (int l = 0; l < 5; l++) {
        if (hd[l] < cnts[l] && s_u[l][hd[l]] > bu) {
          bu = s_u[l][hd[l]];
          bl = l;
        }
      }
      if (bl < 0) break;
      s_pick[t++] = bl * 512 + hd[bl];
      hd[bl]++;
    }
    s_total = t;
  }
  __syncthreads();
  int total = s_total;
  for (int t = tid; t < 100; t += 256) {
    if (t < total) {
      int pk = s_pick[t];
      int l = pk >> 9, r = pk & 511;
      size_t gbase = (size_t)(n * 5 + l) * 512 + r;
#pragma unroll
      for (int q = 0; q < 4; q++)
        out[(n * 100 + t) * 4 + q] = (float)g_box[gbase * 4 + q];
      out[800 + n * 100 + t] = (float)n;
    } else {
#pragma unroll
      for (int q = 0; q < 4; q++) out[(n * 100 + t) * 4 + q] = 0.0f;
      out[800 + n * 100 + t] = -1.0f;
    }
  }
}

extern "C" void kernel_launch(void* const* d_in, const int* in_sizes, int n_in,
                              void* d_out, int out_size, void* d_ws,
                              size_t ws_size, hipStream_t stream) {
  (void)in_sizes; (void)n_in; (void)out_size;
  const float* fmap[5];
  const float* priors[5];
  for (int l = 0; l < 5; l++) {
    fmap[l] = (const float*)d_in[2 * l];        // interleaved input order!
    priors[l] = (const float*)d_in[2 * l + 1];
  }
  const float* conv_w = (const float*)d_in[10];
  const float* conv_b = (const float*)d_in[11];
  const float* log_w = (const float*)d_in[12];
  const float* log_b = (const float*)d_in[13];
  const float* reg_w = (const float*)d_in[14];
  const float* reg_b = (const float*)d_in[15];
  const int* imsizes = (const int*)d_in[16];
  float* out = (float*)d_out;

  bool f64h = ws_size >= (size_t)60000000;

  char* base = (char*)d_ws;
  size_t off = 0;
  auto alloc = [&](size_t bytes) -> void* {
    off = (off + 255) & ~(size_t)255;
    void* p = base + off;
    off += bytes;
    return p;
  };
  void* hraw = alloc(6831616ull * (f64h ? 8 : 4));
  double* logits = (double*)alloc(80058ull * 8);
  double* regs = (double*)alloc(320232ull * 8);
  double* g_box = (double*)alloc(10ull * 512 * 4 * 8);
  unsigned long long* g_u = (unsigned long long*)alloc(10ull * 512 * 8);
  int* g_cnt = (int*)alloc(16 * 4);

  if (f64h) {
    conv_fused_kernel<double><<<CONV_BLOCKS, 256, 0, stream>>>(
        fmap[0], fmap[1], fmap[2], fmap[3], fmap[4], conv_w, conv_b,
        (double*)hraw);
    heads_fused_kernel<double><<<dim3(211, 2), 256, 0, stream>>>(
        (double*)hraw, log_w, log_b, reg_w, reg_b, logits, regs);
  } else {
    conv_fused_kernel<float><<<CONV_BLOCKS, 256, 0, stream>>>(
        fmap[0], fmap[1], fmap[2], fmap[3], fmap[4], conv_w, conv_b,
        (float*)hraw);
    heads_fused_kernel<float><<<dim3(211, 2), 256, 0, stream>>>(
        (float*)hraw, log_w, log_b, reg_w, reg_b, logits, regs);
  }
  topk_nms_kernel<<<10, 1024, 0, stream>>>(
      logits, regs, priors[0], priors[1], priors[2], priors[3], priors[4],
      imsizes, g_box, g_u, g_cnt);
  select_kernel<<<2, 256, 0, stream>>>(g_box, g_u, g_cnt, out);
}

// Round 19
// 998.381 us; speedup vs baseline: 1.0854x; 1.0854x over previous
//
#include <hip/hip_runtime.h>
#include <math.h>

// RPN forward: fused conv3x3+relu (f64 MFMA implicit GEMM, layout-probed,
// raw-weight register loads, dbuf input LDS, 8ci/barrier) -> fused 1x1
// heads -> [topk+decode+per-group sort+NMS+compact] (10 blocks) ->
// per-image merge select. 4 dispatches. FINAL = R15 structure (best:
// 1002us). Precision: f64 everywhere decision-relevant (absmax 0).
// Budget: conv 693us (499us f64-MFMA pipe-busy @92% of 78.6TF spec =
// hard floor for f64-exact), ~190us conv idle (5 structural variants
// bracketed it), ~310us tail (3 restructures R16-R18 all regressed ->
// serial-structure bound at 10-block scale). R18's wave-aggregated
// histogram reverted (ballot loop cost >= serialization it replaced).

#define N_IMG 2
#define C_CH  256
#define D_PER 2147
#define K_TOT 4294
#define CONV_BLOCKS 1912
#define CPX 239              // CONV_BLOCKS / 8 XCDs (exact)

typedef double v4d __attribute__((ext_vector_type(4)));

__constant__ int c_Ml[5]     = {30000, 7500, 1875, 507, 147};
__constant__ int c_kl[5]     = {500, 500, 500, 500, 147};
__constant__ int c_logoff[5] = {0, 60000, 75000, 78750, 79764};   // 6*cumE
__constant__ int c_regoff[5] = {0, 240000, 300000, 315000, 319056}; // 24*cumE
__constant__ int c_fs[5]     = {100, 50, 25, 13, 7};
__constant__ int c_npt[5]    = {13, 7, 4, 2, 1};
__constant__ int c_E[5]      = {10000, 2500, 625, 169, 49};
__constant__ int c_cumbl[6]  = {0, 1352, 1744, 1872, 1904, 1912};
__constant__ int c_hcum[6]   = {0, 157, 197, 207, 210, 211};
__constant__ size_t c_hoff[5] = {0, 5120000, 6400000, 6720000, 6806528};

// ------- fused conv3x3 (SAME) + bias + relu via f64 MFMA -----------------
template <typename T>
__global__ __launch_bounds__(256) void conv_fused_kernel(
    const float* __restrict__ x0, const float* __restrict__ x1,
    const float* __restrict__ x2, const float* __restrict__ x3,
    const float* __restrict__ x4, const float* __restrict__ wraw,
    const float* __restrict__ bias, T* __restrict__ h) {
  __shared__ __align__(16) double s_in[2][960];  // dbuf [ci8][10x12]
  int tid = threadIdx.x;
  int bid = (blockIdx.x & 7) * CPX + (blockIdx.x >> 3);  // XCD swizzle
  int l = 0;
  while (bid >= c_cumbl[l + 1]) ++l;
  int r = bid - c_cumbl[l];
  int fs = c_fs[l], npt = c_npt[l];
  int tiles = npt * npt;
  int tile = r % tiles;
  int cn = r / tiles;
  int cobi = cn & 3, n = cn >> 2;
  int ptx = tile % npt, pty = tile / npt;
  int px0 = ptx * 8, py0 = pty * 8;
  int E = fs * fs;
  const float* xl;
  switch (l) {
    case 0: xl = x0; break;
    case 1: xl = x1; break;
    case 2: xl = x2; break;
    case 3: xl = x3; break;
    default: xl = x4; break;
  }
  const float* xn = xl + (size_t)n * C_CH * E;
  T* hl = h + c_hoff[l];

  int lane = tid & 63;
  int wv = tid >> 6;
  int lx = lane & 15;
  int lk = lane >> 4;

  // ---- layout calibration probes (verified R12) ----
  double ind0 = (lk == 0) ? 1.0 : 0.0;
  v4d pr1 = __builtin_amdgcn_mfma_f64_16x16x4f64((double)lx, ind0,
                                                 (v4d)0.0, 0, 0, 0);
  v4d pr2 = __builtin_amdgcn_mfma_f64_16x16x4f64(ind0, (double)lx,
                                                 (v4d)0.0, 0, 0, 0);
  int coL[4], pxL[4];
#pragma unroll
  for (int q = 0; q < 4; ++q) {
    coL[q] = (int)pr1[q];
    pxL[q] = (int)pr2[q];
  }

  int in_dst[4], in_src[4];
#pragma unroll
  for (int it = 0; it < 4; ++it) {
    int idx = tid + it * 256;
    in_dst[it] = -1;
    in_src[it] = -1;
    if (idx < 800) {
      int ci = idx / 100, rr2 = idx % 100;
      int hy = rr2 / 10, hx = rr2 % 10;
      int gy = py0 - 1 + hy, gx = px0 - 1 + hx;
      in_dst[it] = ci * 120 + hy * 12 + hx;
      if (gy >= 0 && gy < fs && gx >= 0 && gx < fs)
        in_src[it] = ci * E + gy * fs + gx;
    }
  }

  int bOff[4];
#pragma unroll
  for (int p = 0; p < 4; ++p) {
    int pxidx = p * 16 + lx;
    bOff[p] = lk * 120 + (pxidx >> 3) * 12 + (pxidx & 7);
  }

  v4d acc[4];
#pragma unroll
  for (int p = 0; p < 4; ++p) acc[p] = (v4d)0.0;

  const float* wp0 = wraw + (size_t)(cobi * 64 + wv * 16 + lx) * 2304;

  float wcur[18], wnxt[18];
  {
    const float* a = wp0 + lk * 9;
    const float* b = wp0 + (4 + lk) * 9;
#pragma unroll
    for (int t = 0; t < 9; ++t) {
      wcur[t] = a[t];
      wcur[9 + t] = b[t];
    }
  }
  {
    float v0[4];
#pragma unroll
    for (int it = 0; it < 4; ++it)
      v0[it] = (in_dst[it] >= 0 && in_src[it] >= 0) ? xn[in_src[it]] : 0.f;
#pragma unroll
    for (int it = 0; it < 4; ++it)
      if (in_dst[it] >= 0) s_in[0][in_dst[it]] = (double)v0[it];
  }
  __syncthreads();

  for (int it = 0; it < 32; ++it) {
    int buf = it & 1;
    bool more = (it + 1 < 32);
    float inx[4];
    if (more) {
      const float* xc1 = xn + (size_t)(it + 1) * 8 * E;
#pragma unroll
      for (int s = 0; s < 4; ++s)
        inx[s] = (in_dst[s] >= 0 && in_src[s] >= 0) ? xc1[in_src[s]] : 0.f;
      const float* a = wp0 + ((it + 1) * 8 + lk) * 9;
      const float* b = wp0 + ((it + 1) * 8 + 4 + lk) * 9;
#pragma unroll
      for (int t = 0; t < 9; ++t) {
        wnxt[t] = a[t];
        wnxt[9 + t] = b[t];
      }
    }
    const double* bbA = s_in[buf];
    const double* bbB = s_in[buf] + 480;
#pragma unroll
    for (int ky = 0; ky < 3; ++ky) {
#pragma unroll
      for (int kx = 0; kx < 3; ++kx) {
        int tap = ky * 3 + kx;
        int boff = ky * 12 + kx;
        double avA = (double)wcur[tap];
#pragma unroll
        for (int p = 0; p < 4; ++p) {
          acc[p] = __builtin_amdgcn_mfma_f64_16x16x4f64(
              avA, bbA[bOff[p] + boff], acc[p], 0, 0, 0);
        }
      }
    }
#pragma unroll
    for (int ky = 0; ky < 3; ++ky) {
#pragma unroll
      for (int kx = 0; kx < 3; ++kx) {
        int tap = ky * 3 + kx;
        int boff = ky * 12 + kx;
        double avB = (double)wcur[9 + tap];
#pragma unroll
        for (int p = 0; p < 4; ++p) {
          acc[p] = __builtin_amdgcn_mfma_f64_16x16x4f64(
              avB, bbB[bOff[p] + boff], acc[p], 0, 0, 0);
        }
      }
    }
    if (more) {
      double* db = s_in[buf ^ 1];
#pragma unroll
      for (int s = 0; s < 4; ++s)
        if (in_dst[s] >= 0) db[in_dst[s]] = (double)inx[s];
#pragma unroll
      for (int t = 0; t < 18; ++t) wcur[t] = wnxt[t];
    }
    __syncthreads();
  }

#pragma unroll
  for (int p = 0; p < 4; ++p) {
#pragma unroll
    for (int rr2 = 0; rr2 < 4; ++rr2) {
      int pxidx = p * 16 + pxL[rr2];
      int gy = py0 + (pxidx >> 3), gx = px0 + (pxidx & 7);
      int co = cobi * 64 + wv * 16 + coL[rr2];
      if (gy < fs && gx < fs) {
        double v = acc[p][rr2] + (double)bias[co];
        hl[((size_t)n * C_CH + co) * E + gy * fs + gx] = (T)fmax(v, 0.0);
      }
    }
  }
}

// ------- fused 1x1 heads: 64 px x 4 c-groups per block, LDS reduce -------
template <typename T>
__global__ __launch_bounds__(256) void heads_fused_kernel(
    const T* __restrict__ h, const float* __restrict__ logw,
    const float* __restrict__ logb, const float* __restrict__ regw,
    const float* __restrict__ regb, double* __restrict__ logits,
    double* __restrict__ regs) {
  __shared__ float s_wh[256][16];
  __shared__ double s_red[4][15][64];
  int tid = threadIdx.x;
  int n = blockIdx.y;
  int cidx = blockIdx.x;
  int l = 0;
  while (cidx >= c_hcum[l + 1]) ++l;
  int chunk = cidx - c_hcum[l];
  int E = c_E[l];
  int px0 = chunk * 64;
  const T* hl = h + c_hoff[l];
  double* logits_l = logits + c_logoff[l];
  double* regs_l = regs + c_regoff[l];

  for (int idx = tid; idx < 4096; idx += 256) {
    int c = idx >> 4, j = idx & 15;
    float v = 0.f;
    if (j < 3) v = logw[j * 256 + c];
    else if (j < 15) v = regw[(j - 3) * 256 + c];
    s_wh[c][j] = v;
  }
  __syncthreads();

  int p = tid & 63, c4 = tid >> 6;
  int pix = px0 + p;
  bool act = pix < E;
  double acc[15];
#pragma unroll
  for (int j = 0; j < 15; j++) acc[j] = 0.0;
  if (act) {
    const T* hp = hl + ((size_t)n * C_CH + c4 * 64) * E + pix;
    for (int cc = 0; cc < 64; ++cc) {
      double hv = (double)hp[(size_t)cc * E];
      const float* wr = &s_wh[c4 * 64 + cc][0];
#pragma unroll
      for (int j = 0; j < 15; j++)
        acc[j] = fma((double)wr[j], hv, acc[j]);
    }
  }
#pragma unroll
  for (int j = 0; j < 15; j++) s_red[c4][j][p] = acc[j];
  __syncthreads();
  if (act) {
    int M = E * 3;
    for (int j = c4; j < 15; j += 4) {
      double v = s_red[0][j][p] + s_red[1][j][p] + s_red[2][j][p] +
                 s_red[3][j][p];
      if (j < 3) {
        logits_l[(size_t)n * M + pix * 3 + j] = v + (double)logb[j];
      } else {
        int rj = j - 3, a = rj >> 2, coord = rj & 3;
        regs_l[((size_t)n * M + pix * 3 + a) * 4 + coord] =
            v + (double)regb[rj];
      }
    }
  }
}

// ------- topk + decode + per-group sort + NMS + compact (10 blocks) ------
__device__ __forceinline__ unsigned long long d2key(double v) {
  unsigned long long ub = (unsigned long long)__double_as_longlong(v);
  return (ub >> 63) ? ~ub : (ub | 0x8000000000000000ull);
}

#define TK_CH 30
union TkShared {
  struct {
    int histw[16][256];
    int hist[256];
    int sgt[1024];
    int seq[1024];
  } a;
  struct {
    unsigned long long u[512];
    int idx[512];
    int keep[512];
    int ps[512];
    int m;
    double bx[512][4];
    unsigned long long mask[512][8];
  } b;
};

__global__ __launch_bounds__(1024) void topk_nms_kernel(
    const double* __restrict__ logits, const double* __restrict__ regs,
    const float* __restrict__ p0, const float* __restrict__ p1,
    const float* __restrict__ p2, const float* __restrict__ p3,
    const float* __restrict__ p4, const int* __restrict__ imsizes,
    double* __restrict__ g_box, unsigned long long* __restrict__ g_u,
    int* __restrict__ g_cnt) {
  __shared__ TkShared sh;
  __shared__ int s_sel[512];
  __shared__ unsigned long long s_prefix;
  __shared__ int s_r;
  int bid = blockIdx.x;
  int n = bid / 5, l = bid % 5;
  int M = c_Ml[l], k = c_kl[l];
  const double* lg = logits + c_logoff[l] + (size_t)n * M;
  int tid = threadIdx.x;
  if (tid == 0) { s_prefix = 0ull; s_r = k; }

  int chunk = (M + 1023) >> 10;     // <= 30
  int i0 = tid * chunk, i1 = min(M, i0 + chunk);
  int cnt = i1 - i0;
  if (cnt < 0) cnt = 0;
  unsigned long long kv[TK_CH];
#pragma unroll
  for (int q = 0; q < TK_CH; q++)
    if (q < cnt) kv[q] = d2key(lg[i0 + q]);
  int wid = tid >> 6;
  __syncthreads();

  for (int pass = 0; pass < 8; ++pass) {
    int shift = 56 - pass * 8;
    for (int i = tid; i < 4096; i += 1024) ((int*)sh.a.histw)[i] = 0;
    __syncthreads();
    unsigned long long pfx = s_prefix;
    int rr = s_r;
#pragma unroll
    for (int q = 0; q < TK_CH; q++) {
      if (q < cnt) {
        unsigned long long u = kv[q];
        if (pass == 0 || (u >> (shift + 8)) == pfx)
          atomicAdd(&sh.a.histw[wid][(int)((u >> shift) & 255ull)], 1);
      }
    }
    __syncthreads();
    if (tid < 256) {
      int s = 0;
#pragma unroll
      for (int w = 0; w < 16; w++) s += sh.a.histw[w][tid];
      sh.a.hist[tid] = s;
    }
    __syncthreads();
    if (tid == 0) {
      int s = 0, beta = 0;
      for (int b = 255; b >= 0; --b) {
        if (s + sh.a.hist[b] >= rr) { beta = b; break; }
        s += sh.a.hist[b];
      }
      s_prefix = (pfx << 8) | (unsigned long long)beta;
      s_r = rr - s;
    }
    __syncthreads();
  }
  unsigned long long T = s_prefix;
  int need = s_r;
  int cgt = 0, ceq = 0;
#pragma unroll
  for (int q = 0; q < TK_CH; q++) {
    if (q < cnt) {
      cgt += (kv[q] > T);
      ceq += (kv[q] == T);
    }
  }
  sh.a.sgt[tid] = cgt;
  sh.a.seq[tid] = ceq;
  __syncthreads();
  for (int o = 1; o < 1024; o <<= 1) {
    int a = (tid >= o) ? sh.a.sgt[tid - o] : 0;
    int b2 = (tid >= o) ? sh.a.seq[tid - o] : 0;
    __syncthreads();
    sh.a.sgt[tid] += a;
    sh.a.seq[tid] += b2;
    __syncthreads();
  }
  int gt_total = sh.a.sgt[1023];
  int pg = sh.a.sgt[tid] - cgt, pe = sh.a.seq[tid] - ceq;
#pragma unroll
  for (int q = 0; q < TK_CH; q++) {
    if (q < cnt) {
      unsigned long long u = kv[q];
      if (u > T) {
        s_sel[pg++] = i0 + q;
      } else if (u == T) {
        if (pe < need) s_sel[gt_total + pe] = i0 + q;
        pe++;
      }
    }
  }
  __syncthreads();

  const float* pp;
  switch (l) {
    case 0: pp = p0; break;
    case 1: pp = p1; break;
    case 2: pp = p2; break;
    case 3: pp = p3; break;
    default: pp = p4; break;
  }
  const double* regs_l = regs + c_regoff[l];
  double imh = (double)imsizes[n * 2 + 0], imw = (double)imsizes[n * 2 + 1];
  const double BCLIP = 4.1351665567423560;
  if (tid < 512) {
    unsigned long long key = 0ull;
    sh.b.idx[tid] = tid;
    sh.b.keep[tid] = 0;
    if (tid < k) {
      int aidx = s_sel[tid];
      double lv = lg[aidx];
      double obj = 1.0 / (1.0 + exp(-lv));
      const double* rp = regs_l + ((size_t)n * M + aidx) * 4;
      const float* pr = pp + (size_t)aidx * 4;
      double px1 = pr[0], py1 = pr[1], px2 = pr[2], py2 = pr[3];
      double pw = px2 - px1, ph = py2 - py1;
      double pcx = px1 + 0.5 * pw, pcy = py1 + 0.5 * ph;
      double dx = rp[0], dy = rp[1];
      double dw = fmin(rp[2], BCLIP), dh = fmin(rp[3], BCLIP);
      double cx = dx * pw + pcx, cy = dy * ph + pcy;
      double w = exp(dw) * pw, hh = exp(dh) * ph;
      double x1 = cx - 0.5 * w, y1 = cy - 0.5 * hh;
      double x2 = cx + 0.5 * w, y2 = cy + 0.5 * hh;
      x1 = fmin(fmax(x1, 0.0), imw);
      x2 = fmin(fmax(x2, 0.0), imw);
      y1 = fmin(fmax(y1, 0.0), imh);
      y2 = fmin(fmax(y2, 0.0), imh);
      bool valid = (obj >= 0.5) && ((x2 - x1) >= 1.0) && ((y2 - y1) >= 1.0);
      sh.b.bx[tid][0] = x1;
      sh.b.bx[tid][1] = y1;
      sh.b.bx[tid][2] = x2;
      sh.b.bx[tid][3] = y2;
      if (valid) key = d2key(obj);
    }
    sh.b.u[tid] = key;
  }
  if (tid == 0) sh.b.m = 0;
  __syncthreads();

  for (int kk = 2; kk <= 512; kk <<= 1) {
    for (int j = kk >> 1; j > 0; j >>= 1) {
      if (tid < 512) {
        int i = tid, ixj = i ^ j;
        if (ixj > i) {
          unsigned long long ua = sh.b.u[i], ub = sh.b.u[ixj];
          int ia = sh.b.idx[i], ib = sh.b.idx[ixj];
          bool up = ((i & kk) == 0);
          bool aAfterB = (ua < ub) || (ua == ub && ia > ib);
          bool sw = up ? aAfterB : !aAfterB && (ua != ub || ia != ib);
          if (sw) {
            sh.b.u[i] = ub; sh.b.u[ixj] = ua;
            sh.b.idx[i] = ib; sh.b.idx[ixj] = ia;
          }
        }
      }
      __syncthreads();
    }
  }
  if (tid < 512) {
    if (sh.b.u[tid] != 0ull && (tid == 511 || sh.b.u[tid + 1] == 0ull))
      sh.b.m = tid + 1;
  }
  __syncthreads();
  int m = sh.b.m;

  if (tid < 512 && tid < m) {
    int i = tid;
    const double* A = sh.b.bx[sh.b.idx[i]];
    double ax1 = A[0], ay1 = A[1], ax2 = A[2], ay2 = A[3];
    double areaA = (ax2 - ax1) * (ay2 - ay1);
    unsigned long long row[8] = {0, 0, 0, 0, 0, 0, 0, 0};
    for (int j = i + 1; j < m; ++j) {
      const double* B = sh.b.bx[sh.b.idx[j]];
      double bx1 = B[0], by1 = B[1], bx2 = B[2], by2 = B[3];
      double areaB = (bx2 - bx1) * (by2 - by1);
      double lx = fmax(ax1, bx1), ly = fmax(ay1, by1);
      double rx = fmin(ax2, bx2), ry = fmin(ay2, by2);
      double iw = fmax(rx - lx, 0.0), ih = fmax(ry - ly, 0.0);
      double inter = iw * ih;
      double iou = inter / (areaA + areaB - inter + 1e-9);
      if (iou > 0.7) row[j >> 6] |= (1ull << (j & 63));
    }
#pragma unroll
    for (int w2 = 0; w2 < 8; ++w2) sh.b.mask[i][w2] = row[w2];
  }
  __syncthreads();

  if (tid == 0) {
    unsigned long long remv[8] = {0, 0, 0, 0, 0, 0, 0, 0};
    for (int i = 0; i < m; ++i) {
      if (!((remv[i >> 6] >> (i & 63)) & 1ull)) {
        sh.b.keep[i] = 1;
#pragma unroll
        for (int w2 = 0; w2 < 8; ++w2) remv[w2] |= sh.b.mask[i][w2];
      }
    }
  }
  __syncthreads();

  if (tid < 512) sh.b.ps[tid] = sh.b.keep[tid];
  __syncthreads();
  for (int o = 1; o < 512; o <<= 1) {
    int v = 0;
    if (tid < 512 && tid >= o) v = sh.b.ps[tid - o];
    __syncthreads();
    if (tid < 512) sh.b.ps[tid] += v;
    __syncthreads();
  }
  if (tid < 512 && sh.b.keep[tid]) {
    int pos = sh.b.ps[tid] - 1;
    const double* B = sh.b.bx[sh.b.idx[tid]];
    size_t gbase = (size_t)bid * 512 + pos;
#pragma unroll
    for (int q = 0; q < 4; q++) g_box[gbase * 4 + q] = B[q];
    g_u[gbase] = sh.b.u[tid];
  }
  if (tid == 0) g_cnt[bid] = (m > 0) ? sh.b.ps[511] : 0;
}

// ------- per-image select: 5-way merge of sorted kept lists, top 100 -----
__global__ __launch_bounds__(256) void select_kernel(
    const double* __restrict__ g_box, const unsigned long long* __restrict__ g_u,
    const int* __restrict__ g_cnt, float* __restrict__ out) {
  __shared__ unsigned long long s_u[5][512];
  __shared__ int s_pick[100];
  __shared__ int s_total;
  int n = blockIdx.x;
  int tid = threadIdx.x;
  int cnts[5];
#pragma unroll
  for (int l = 0; l < 5; l++) cnts[l] = g_cnt[n * 5 + l];
  for (int idx = tid; idx < 5 * 512; idx += 256) {
    int l = idx >> 9, r = idx & 511;
    s_u[l][r] = (r < cnts[l]) ? g_u[(size_t)(n * 5 + l) * 512 + r] : 0ull;
  }
  __syncthreads();
  if (tid == 0) {
    int hd[5] = {0, 0, 0, 0, 0};
    int t = 0;
    while (t < 100) {
      int bl = -1;
      unsigned long long bu = 0ull;
      for (int l = 0; l < 5; l++) {
        if (hd[l] < cnts[l] && s_u[l][hd[l]] > bu) {
          bu = s_u[l][hd[l]];
          bl = l;
        }
      }
      if (bl < 0) break;
      s_pick[t++] = bl * 512 + hd[bl];
      hd[bl]++;
    }
    s_total = t;
  }
  __syncthreads();
  int total = s_total;
  for (int t = tid; t < 100; t += 256) {
    if (t < total) {
      int pk = s_pick[t];
      int l = pk >> 9, r = pk & 511;
      size_t gbase = (size_t)(n * 5 + l) * 512 + r;
#pragma unroll
      for (int q = 0; q < 4; q++)
        out[(n * 100 + t) * 4 + q] = (float)g_box[gbase * 4 + q];
      out[800 + n * 100 + t] = (float)n;
    } else {
#pragma unroll
      for (int q = 0; q < 4; q++) out[(n * 100 + t) * 4 + q] = 0.0f;
      out[800 + n * 100 + t] = -1.0f;
    }
  }
}

extern "C" void kernel_launch(void* const* d_in, const int* in_sizes, int n_in,
                              void* d_out, int out_size, void* d_ws,
                              size_t ws_size, hipStream_t stream) {
  (void)in_sizes; (void)n_in; (void)out_size;
  const float* fmap[5];
  const float* priors[5];
  for (int l = 0; l < 5; l++) {
    fmap[l] = (const float*)d_in[2 * l];        // interleaved input order!
    priors[l] = (const float*)d_in[2 * l + 1];
  }
  const float* conv_w = (const float*)d_in[10];
  const float* conv_b = (const float*)d_in[11];
  const float* log_w = (const float*)d_in[12];
  const float* log_b = (const float*)d_in[13];
  const float* reg_w = (const float*)d_in[14];
  const float* reg_b = (const float*)d_in[15];
  const int* imsizes = (const int*)d_in[16];
  float* out = (float*)d_out;

  bool f64h = ws_size >= (size_t)60000000;

  char* base = (char*)d_ws;
  size_t off = 0;
  auto alloc = [&](size_t bytes) -> void* {
    off = (off + 255) & ~(size_t)255;
    void* p = base + off;
    off += bytes;
    return p;
  };
  void* hraw = alloc(6831616ull * (f64h ? 8 : 4));
  double* logits = (double*)alloc(80058ull * 8);
  double* regs = (double*)alloc(320232ull * 8);
  double* g_box = (double*)alloc(10ull * 512 * 4 * 8);
  unsigned long long* g_u = (unsigned long long*)alloc(10ull * 512 * 8);
  int* g_cnt = (int*)alloc(16 * 4);

  if (f64h) {
    conv_fused_kernel<double><<<CONV_BLOCKS, 256, 0, stream>>>(
        fmap[0], fmap[1], fmap[2], fmap[3], fmap[4], conv_w, conv_b,
        (double*)hraw);
    heads_fused_kernel<double><<<dim3(211, 2), 256, 0, stream>>>(
        (double*)hraw, log_w, log_b, reg_w, reg_b, logits, regs);
  } else {
    conv_fused_kernel<float><<<CONV_BLOCKS, 256, 0, stream>>>(
        fmap[0], fmap[1], fmap[2], fmap[3], fmap[4], conv_w, conv_b,
        (float*)hraw);
    heads_fused_kernel<float><<<dim3(211, 2), 256, 0, stream>>>(
        (float*)hraw, log_w, log_b, reg_w, reg_b, logits, regs);
  }
  topk_nms_kernel<<<10, 1024, 0, stream>>>(
      logits, regs, priors[0], priors[1], priors[2], priors[3], priors[4],
      imsizes, g_box, g_u, g_cnt);
  select_kernel<<<2, 256, 0, stream>>>(g_box, g_u, g_cnt, out);
}